// Round 7
// baseline (288.850 us; speedup 1.0000x reference)
//
#include <hip/hip_runtime.h>
#include <stdint.h>

typedef __attribute__((ext_vector_type(8))) __bf16 bf16x8;
typedef __attribute__((ext_vector_type(4))) float f32x4;
typedef __attribute__((ext_vector_type(8))) unsigned short ushort8;
typedef __attribute__((ext_vector_type(4))) unsigned short ushort4v;
typedef unsigned short u16;
typedef unsigned int u32;
typedef __attribute__((ext_vector_type(4))) u32 u32x4;

__device__ __forceinline__ u16 f2bf(float f) {
    __bf16 h = (__bf16)f;
    return __builtin_bit_cast(u16, h);
}

__device__ __forceinline__ f32x4 mfma16(bf16x8 a, bf16x8 b, f32x4 c) {
    return __builtin_amdgcn_mfma_f32_16x16x32_bf16(a, b, c, 0, 0, 0);
}

typedef __attribute__((address_space(1))) const char g_char;
typedef __attribute__((address_space(3))) char l_char;
__device__ __forceinline__ void gload_lds16(const void* g, void* l) {
    __builtin_amdgcn_global_load_lds((g_char*)g, (l_char*)l, 16, 0, 0);
}

// ---------------------------------------------------------------------------
// Weight prep: WT[j][k] = W_sel[k][j%256] as bf16 (j<256:Wq, <512:Wk, <768:Wv)
//              WOT[o][h] = Wo[h][o] as bf16
// ---------------------------------------------------------------------------
__global__ __launch_bounds__(256) void prep_w(
    const float* __restrict__ Wq, const float* __restrict__ Wk,
    const float* __restrict__ Wv, const float* __restrict__ Wo,
    u16* __restrict__ WT, u16* __restrict__ WOT)
{
    int idx = blockIdx.x * 256 + threadIdx.x;  // 0..262143
    if (idx < 196608) {
        int j = idx >> 8, k = idx & 255;
        const float* W = (j < 256) ? Wq : (j < 512) ? Wk : Wv;
        WT[idx] = f2bf(W[k * 256 + (j & 255)]);
    } else {
        int t = idx - 196608;
        int j = t >> 8, k = t & 255;
        WOT[t] = f2bf(Wo[k * 256 + j]);
    }
}

// ---------------------------------------------------------------------------
// mask_pack: coalesced LDS-staged bit-pack, layout matched to attn lanes.
// Block y <-> attn block x=y. For (wid, lane=(lr,lg), k):
//   word bit (kl*16 + ct*4 + j) = Mask[b][n0+lg*4+j][(2k+kl)*64+ct*16+lr] > 0.5
//   stored at MP[((y*8+wid)*64+lane)*4 + k]  (one u32x4 per attn lane)
// ---------------------------------------------------------------------------
__global__ __launch_bounds__(256) void mask_pack(
    const float* __restrict__ Mask, u32* __restrict__ MP)
{
    __shared__ float mlds[16 * 516];  // padded rows (516 f32) vs bank conflicts
    const int y = blockIdx.x;         // 0..511
    const int tid = threadIdx.x;
    const int b = y & 127, rb = y >> 7;
    const int lane = tid & 63, k = tid >> 6;
    const int lr = lane & 15, lg = lane >> 4;

    for (int wid = 0; wid < 8; ++wid) {
        int n0 = rb * 128 + wid * 16;
        const float* src = Mask + ((size_t)b * 512 + n0) * 512;
        __syncthreads();  // protect mlds from previous iteration's readers
        #pragma unroll
        for (int i = 0; i < 8; ++i) {
            int e = (i * 256 + tid) * 4;
            int r = e >> 9, key = e & 511;
            f32x4 v = __builtin_nontemporal_load(
                reinterpret_cast<const f32x4*>(src + (size_t)r * 512 + key));
            *reinterpret_cast<f32x4*>(&mlds[r * 516 + key]) = v;
        }
        __syncthreads();
        u32 w = 0;
        #pragma unroll
        for (int kl = 0; kl < 2; ++kl) {
            int kt = k * 2 + kl;
            #pragma unroll
            for (int ct = 0; ct < 4; ++ct)
                #pragma unroll
                for (int j = 0; j < 4; ++j) {
                    float v = mlds[(lg * 4 + j) * 516 + kt * 64 + ct * 16 + lr];
                    w |= (v > 0.5f ? 1u : 0u) << (kl * 16 + ct * 4 + j);
                }
        }
        MP[((size_t)(y * 8 + wid) * 64 + lane) * 4 + k] = w;
    }
}

// ---------------------------------------------------------------------------
// QKV projection: C[65536,768] = relu(X[65536,256] @ W + b), bf16 out.
// ---------------------------------------------------------------------------
__global__ __launch_bounds__(256, 2) void qkv_gemm(
    const float* __restrict__ X, const u16* __restrict__ WT,
    const float* __restrict__ bQ, const float* __restrict__ bK,
    const float* __restrict__ bV,
    u16* __restrict__ outQ, u16* __restrict__ outK, u16* __restrict__ outVT)
{
    __shared__ __align__(16) u16 As[128 * 256];  // 64KB, XOR-swizzled rows
    __shared__ __align__(16) u16 Bs[128 * 64];   // 16KB, XOR-swizzled rows
    const int tid = threadIdx.x;
    const int m0 = blockIdx.x * 128;

    #pragma unroll
    for (int i = 0; i < 32; ++i) {
        int flat = (i * 256 + tid) * 4;
        int r = flat >> 8, c = flat & 255;
        const f32x4 f = *reinterpret_cast<const f32x4*>(X + (size_t)(m0 + r) * 256 + c);
        ushort4v h;
        h.x = f2bf(f.x); h.y = f2bf(f.y); h.z = f2bf(f.z); h.w = f2bf(f.w);
        int byte = (r * 512 + c * 2) ^ ((r & 7) << 4);
        *reinterpret_cast<ushort4v*>(reinterpret_cast<char*>(As) + byte) = h;
    }

    const int lane = tid & 63, wid = tid >> 6;
    const int wr = wid >> 1, wc = wid & 1;
    const int lr = lane & 15, lg = lane >> 4;

    for (int cb = 0; cb < 6; ++cb) {
        const int jbase = cb * 128;
        f32x4 acc[4][4];
        #pragma unroll
        for (int a = 0; a < 4; ++a)
            #pragma unroll
            for (int b = 0; b < 4; ++b) acc[a][b] = (f32x4){0.f, 0.f, 0.f, 0.f};

        for (int kk = 0; kk < 256; kk += 64) {
            __syncthreads();
            #pragma unroll
            for (int i = 0; i < 4; ++i) {
                int e = (i * 256 + tid) * 8;
                int r = e >> 6, c = e & 63;
                ushort8 d = *reinterpret_cast<const ushort8*>(WT + (size_t)(jbase + r) * 256 + kk + c);
                int byte = (r * 128 + c * 2) ^ ((r & 7) << 4);
                *reinterpret_cast<ushort8*>(reinterpret_cast<char*>(Bs) + byte) = d;
            }
            __syncthreads();
            #pragma unroll
            for (int ks = 0; ks < 2; ++ks) {
                bf16x8 af[4], bfr[4];
                #pragma unroll
                for (int mt = 0; mt < 4; ++mt) {
                    int r = wr * 64 + mt * 16 + lr;
                    int byte = (r * 512 + (kk + ks * 32 + lg * 8) * 2) ^ ((r & 7) << 4);
                    af[mt] = *reinterpret_cast<const bf16x8*>(reinterpret_cast<const char*>(As) + byte);
                }
                #pragma unroll
                for (int nt = 0; nt < 4; ++nt) {
                    int r = wc * 64 + nt * 16 + lr;
                    int byte = (r * 128 + (ks * 32 + lg * 8) * 2) ^ ((r & 7) << 4);
                    bfr[nt] = *reinterpret_cast<const bf16x8*>(reinterpret_cast<const char*>(Bs) + byte);
                }
                #pragma unroll
                for (int mt = 0; mt < 4; ++mt)
                    #pragma unroll
                    for (int nt = 0; nt < 4; ++nt)
                        acc[mt][nt] = mfma16(af[mt], bfr[nt], acc[mt][nt]);
            }
        }
        const float* bias = (cb < 2) ? bQ : (cb < 4) ? bK : bV;
        float bcol[4];
        #pragma unroll
        for (int nt = 0; nt < 4; ++nt)
            bcol[nt] = bias[(jbase + wc * 64 + nt * 16 + lr) & 255];
        #pragma unroll
        for (int mt = 0; mt < 4; ++mt) {
            #pragma unroll
            for (int nt = 0; nt < 4; ++nt) {
                #pragma unroll
                for (int j = 0; j < 4; ++j) {
                    float v = fmaxf(acc[mt][nt][j] + bcol[nt], 0.f);
                    u16 h = f2bf(v);
                    int row = m0 + wr * 64 + mt * 16 + lg * 4 + j;
                    int col = jbase + wc * 64 + nt * 16 + lr;
                    if (cb < 2) {
                        outQ[(size_t)row * 256 + col] = h;
                    } else if (cb < 4) {
                        outK[(size_t)row * 256 + (col - 256)] = h;
                    } else {
                        int bb = row >> 9, n = row & 511;
                        outVT[(size_t)bb * 131072 + (size_t)(col - 512) * 512 + n] = h;
                    }
                }
            }
        }
    }
}

// ---------------------------------------------------------------------------
// Flash attention r7: KVBLK=64 (8 barriers), K LDS-dbuf via gload_lds
// (pre-swizzled source), V read directly from global (L2-resident, shared by
// the 4 same-XCD blocks of a batch), mask = one u32x4 per lane for the whole
// kernel (pre-packed), PV in two 32-key halves through per-wave p_lds.
// ---------------------------------------------------------------------------
__global__ __launch_bounds__(512) void attn_kernel(
    const u16* __restrict__ Q, const u16* __restrict__ K,
    const u16* __restrict__ VT, const u32* __restrict__ MP,
    u16* __restrict__ Out)
{
    __shared__ __align__(16) u16 k_lds[2][64 * 256];  // 2 x 32KB, XOR-swizzled
    __shared__ __align__(16) u16 p_lds[8][16 * 36];   // 72B rows, per-wave
    const int tid = threadIdx.x;          // 0..511
    const int x = blockIdx.x;
    const int b = x & 127, rb = x >> 7;   // batch-major -> same XCD per batch
    const int lane = tid & 63, wid = tid >> 6;
    const int lr = lane & 15, lg = lane >> 4;
    const int n0 = rb * 128 + wid * 16;
    const u16* qbat = Q  + (size_t)b * 131072;
    const u16* kbat = K  + (size_t)b * 131072;
    const u16* vbat = VT + (size_t)b * 131072;

    // whole-kernel mask bits for this lane: 4 u32 (8 kt x 16 bits)
    u32x4 mw = *reinterpret_cast<const u32x4*>(
        MP + ((size_t)(x * 8 + wid) * 64 + lane) * 4);

    auto stage = [&](int buf, int kt) {
        #pragma unroll
        for (int i = 0; i < 4; ++i) {
            int p = (i * 512 + tid) * 16;
            int krow = p >> 9, kcol2 = p & 511;
            int scol2 = kcol2 ^ ((krow & 7) << 4);
            const char* gk = reinterpret_cast<const char*>(
                kbat + (size_t)(kt * 64 + krow) * 256) + scol2;
            char* lk = reinterpret_cast<char*>(k_lds[buf]) + i * 8192 + wid * 1024;
            gload_lds16(gk, lk);
        }
    };
    stage(0, 0);

    f32x4 acc[16];
    #pragma unroll
    for (int i = 0; i < 16; ++i) acc[i] = (f32x4){0.f, 0.f, 0.f, 0.f};
    float mreg[4], lreg[4];
    #pragma unroll
    for (int j = 0; j < 4; ++j) { mreg[j] = -__builtin_inff(); lreg[j] = 0.f; }

    __syncthreads();

    for (int kt = 0; kt < 8; ++kt) {
        const int cur = kt & 1;
        if (kt < 7) stage(cur ^ 1, kt + 1);

        const u32 mb = (mw[kt >> 1] >> ((kt & 1) * 16)) & 0xFFFFu;

        // ---- QK^T: 16 rows x 64 keys per wave ----
        f32x4 s[4];
        #pragma unroll
        for (int ct = 0; ct < 4; ++ct) s[ct] = (f32x4){0.f, 0.f, 0.f, 0.f};
        const char* kbase = reinterpret_cast<const char*>(k_lds[cur]);
        __builtin_amdgcn_s_setprio(1);
        #pragma unroll
        for (int ks = 0; ks < 8; ++ks) {
            bf16x8 qv = *reinterpret_cast<const bf16x8*>(
                qbat + (size_t)(n0 + lr) * 256 + ks * 32 + lg * 8);
            #pragma unroll
            for (int ct = 0; ct < 4; ++ct) {
                int krow = ct * 16 + lr;
                int byte = (krow * 512 + ks * 64 + lg * 16) ^ ((krow & 7) << 4);
                bf16x8 kf = *reinterpret_cast<const bf16x8*>(kbase + byte);
                s[ct] = mfma16(qv, kf, s[ct]);
            }
        }
        __builtin_amdgcn_s_setprio(0);

        // ---- mask select + online softmax (defer-rescale) ----
        float p[4][4];
        #pragma unroll
        for (int ct = 0; ct < 4; ++ct)
            #pragma unroll
            for (int j = 0; j < 4; ++j)
                p[ct][j] = ((mb >> (ct * 4 + j)) & 1u) ? s[ct][j] : -9.0e15f;

        float r0j[4];
        bool need = false;
        #pragma unroll
        for (int j = 0; j < 4; ++j) {
            float r0 = fmaxf(fmaxf(p[0][j], p[1][j]), fmaxf(p[2][j], p[3][j]));
            r0 = fmaxf(r0, __shfl_xor(r0, 1));
            r0 = fmaxf(r0, __shfl_xor(r0, 2));
            r0 = fmaxf(r0, __shfl_xor(r0, 4));
            r0 = fmaxf(r0, __shfl_xor(r0, 8));
            r0j[j] = r0;
            need = need || (r0 > mreg[j]);
        }
        if (__any(need)) {
            #pragma unroll
            for (int j = 0; j < 4; ++j) {
                float mnew = fmaxf(mreg[j], r0j[j]);
                float sc = __expf(mreg[j] - mnew);
                mreg[j] = mnew;
                lreg[j] *= sc;
                #pragma unroll
                for (int ht = 0; ht < 16; ++ht) acc[ht][j] *= sc;
            }
        }
        #pragma unroll
        for (int j = 0; j < 4; ++j) {
            float ps = 0.f;
            #pragma unroll
            for (int ct = 0; ct < 4; ++ct) {
                float e = __expf(p[ct][j] - mreg[j]);
                p[ct][j] = e;
                ps += e;
            }
            lreg[j] += ps;
        }

        // ---- PV in two 32-key halves: per-wave p_lds, V from global/L2 ----
        #pragma unroll
        for (int ks2 = 0; ks2 < 2; ++ks2) {
            #pragma unroll
            for (int cth = 0; cth < 2; ++cth) {
                int ct = ks2 * 2 + cth;
                #pragma unroll
                for (int j = 0; j < 4; ++j) {
                    int byte = (lg * 4 + j) * 72 + (cth * 16 + lr) * 2;
                    *reinterpret_cast<u16*>(reinterpret_cast<char*>(p_lds[wid]) + byte)
                        = f2bf(p[ct][j]);
                }
            }
            bf16x8 pf = *reinterpret_cast<const bf16x8*>(
                reinterpret_cast<const char*>(p_lds[wid]) + lr * 72 + lg * 16);
            __builtin_amdgcn_s_setprio(1);
            #pragma unroll
            for (int ht = 0; ht < 16; ++ht) {
                bf16x8 vf = *reinterpret_cast<const bf16x8*>(
                    vbat + (size_t)(ht * 16 + lr) * 512 + kt * 64 + ks2 * 32 + lg * 8);
                acc[ht] = mfma16(pf, vf, acc[ht]);
            }
            __builtin_amdgcn_s_setprio(0);
        }

        __syncthreads();  // next K tile staged (vmcnt drained); k_lds reads done
    }

    // finalize: normalize and store bf16
    #pragma unroll
    for (int j = 0; j < 4; ++j) {
        float lt = lreg[j];
        lt += __shfl_xor(lt, 1);
        lt += __shfl_xor(lt, 2);
        lt += __shfl_xor(lt, 4);
        lt += __shfl_xor(lt, 8);
        float inv = 1.0f / lt;
        int qn = n0 + lg * 4 + j;
        u16* orow = Out + ((size_t)b * 512 + qn) * 256;
        #pragma unroll
        for (int ht = 0; ht < 16; ++ht)
            orow[ht * 16 + lr] = f2bf(acc[ht][j] * inv);
    }
}

// ---------------------------------------------------------------------------
// Output projection: Out[65536,256] = relu(A[65536,256](bf16) @ Wo + bo), f32.
// ---------------------------------------------------------------------------
__global__ __launch_bounds__(256, 2) void out_gemm(
    const u16* __restrict__ A, const u16* __restrict__ WOT,
    const float* __restrict__ bO, float* __restrict__ Out)
{
    __shared__ __align__(16) u16 As[128 * 256];
    __shared__ __align__(16) u16 Bs[128 * 64];
    const int tid = threadIdx.x;
    const int m0 = blockIdx.x * 128;

    #pragma unroll
    for (int i = 0; i < 16; ++i) {
        int e = (i * 256 + tid) * 8;
        int r = e >> 8, c = e & 255;
        ushort8 d = *reinterpret_cast<const ushort8*>(A + (size_t)(m0 + r) * 256 + c);
        int byte = (r * 512 + c * 2) ^ ((r & 7) << 4);
        *reinterpret_cast<ushort8*>(reinterpret_cast<char*>(As) + byte) = d;
    }

    const int lane = tid & 63, wid = tid >> 6;
    const int wr = wid >> 1, wc = wid & 1;
    const int lr = lane & 15, lg = lane >> 4;

    for (int cb = 0; cb < 2; ++cb) {
        const int jbase = cb * 128;
        f32x4 acc[4][4];
        #pragma unroll
        for (int a = 0; a < 4; ++a)
            #pragma unroll
            for (int b = 0; b < 4; ++b) acc[a][b] = (f32x4){0.f, 0.f, 0.f, 0.f};

        for (int kk = 0; kk < 256; kk += 64) {
            __syncthreads();
            #pragma unroll
            for (int i = 0; i < 4; ++i) {
                int e = (i * 256 + tid) * 8;
                int r = e >> 6, c = e & 63;
                ushort8 d = *reinterpret_cast<const ushort8*>(WOT + (size_t)(jbase + r) * 256 + kk + c);
                int byte = (r * 128 + c * 2) ^ ((r & 7) << 4);
                *reinterpret_cast<ushort8*>(reinterpret_cast<char*>(Bs) + byte) = d;
            }
            __syncthreads();
            #pragma unroll
            for (int ks = 0; ks < 2; ++ks) {
                bf16x8 af[4], bfr[4];
                #pragma unroll
                for (int mt = 0; mt < 4; ++mt) {
                    int r = wr * 64 + mt * 16 + lr;
                    int byte = (r * 512 + (kk + ks * 32 + lg * 8) * 2) ^ ((r & 7) << 4);
                    af[mt] = *reinterpret_cast<const bf16x8*>(reinterpret_cast<const char*>(As) + byte);
                }
                #pragma unroll
                for (int nt = 0; nt < 4; ++nt) {
                    int r = wc * 64 + nt * 16 + lr;
                    int byte = (r * 128 + (ks * 32 + lg * 8) * 2) ^ ((r & 7) << 4);
                    bfr[nt] = *reinterpret_cast<const bf16x8*>(reinterpret_cast<const char*>(Bs) + byte);
                }
                #pragma unroll
                for (int mt = 0; mt < 4; ++mt)
                    #pragma unroll
                    for (int nt = 0; nt < 4; ++nt)
                        acc[mt][nt] = mfma16(af[mt], bfr[nt], acc[mt][nt]);
            }
        }
        float bcol[4];
        #pragma unroll
        for (int nt = 0; nt < 4; ++nt)
            bcol[nt] = bO[jbase + wc * 64 + nt * 16 + lr];
        #pragma unroll
        for (int mt = 0; mt < 4; ++mt) {
            #pragma unroll
            for (int nt = 0; nt < 4; ++nt) {
                #pragma unroll
                for (int j = 0; j < 4; ++j) {
                    float v = fmaxf(acc[mt][nt][j] + bcol[nt], 0.f);
                    int row = m0 + wr * 64 + mt * 16 + lg * 4 + j;
                    int col = jbase + wc * 64 + nt * 16 + lr;
                    Out[(size_t)row * 256 + col] = v;
                }
            }
        }
    }
}

// ---------------------------------------------------------------------------
extern "C" void kernel_launch(void* const* d_in, const int* in_sizes, int n_in,
                              void* d_out, int out_size, void* d_ws, size_t ws_size,
                              hipStream_t stream) {
    const float* x    = (const float*)d_in[0];
    const float* mask = (const float*)d_in[1];
    const float* Wv   = (const float*)d_in[2];
    const float* bv   = (const float*)d_in[3];
    const float* Wk   = (const float*)d_in[4];
    const float* bk   = (const float*)d_in[5];
    const float* Wq   = (const float*)d_in[6];
    const float* bq   = (const float*)d_in[7];
    const float* Wo   = (const float*)d_in[8];
    const float* bo   = (const float*)d_in[9];
    float* out = (float*)d_out;

    char* ws = (char*)d_ws;
    u16* WT  = (u16*)(ws);                          // 768*256 bf16 = 384KB
    u16* WOT = (u16*)(ws + 393216);                 // 256*256 bf16 = 128KB
    u16* Qb  = (u16*)(ws + 524288);                 // 33.55MB (also attn out)
    u16* Kb  = (u16*)(ws + 524288 + 33554432);      // 33.55MB
    u16* VTb = (u16*)(ws + 524288 + 2 * 33554432);  // 33.55MB, [b][h][n]
    // packed mask (4MB) in d_out scratch; out_gemm overwrites it later
    u32* MPk = (u32*)d_out;

    prep_w<<<1024, 256, 0, stream>>>(Wq, Wk, Wv, Wo, WT, WOT);
    mask_pack<<<512, 256, 0, stream>>>(mask, MPk);
    qkv_gemm<<<512, 256, 0, stream>>>(x, WT, bq, bk, bv, Qb, Kb, VTb);
    attn_kernel<<<512, 512, 0, stream>>>(Qb, Kb, VTb, MPk, Qb);
    out_gemm<<<512, 256, 0, stream>>>(Qb, WOT, bo, out);
}

// Round 8
// 196.540 us; speedup vs baseline: 1.4697x; 1.4697x over previous
//
#include <hip/hip_runtime.h>
#include <stdint.h>

typedef __attribute__((ext_vector_type(8))) __bf16 bf16x8;
typedef __attribute__((ext_vector_type(4))) float f32x4;
typedef __attribute__((ext_vector_type(8))) unsigned short ushort8;
typedef __attribute__((ext_vector_type(4))) unsigned short ushort4v;
typedef unsigned short u16;
typedef unsigned int u32;

__device__ __forceinline__ u16 f2bf(float f) {
    __bf16 h = (__bf16)f;
    return __builtin_bit_cast(u16, h);
}

__device__ __forceinline__ f32x4 mfma16(bf16x8 a, bf16x8 b, f32x4 c) {
    return __builtin_amdgcn_mfma_f32_16x16x32_bf16(a, b, c, 0, 0, 0);
}

typedef __attribute__((address_space(1))) const char g_char;
typedef __attribute__((address_space(3))) char l_char;
__device__ __forceinline__ void gload_lds16(const void* g, void* l) {
    __builtin_amdgcn_global_load_lds((g_char*)g, (l_char*)l, 16, 0, 0);
}

// ---------------------------------------------------------------------------
// Weight prep: WT[j][k] = W_sel[k][j%256] as bf16 (j<256:Wq, <512:Wk, <768:Wv)
//              WOT[o][h] = Wo[h][o] as bf16
// ---------------------------------------------------------------------------
__global__ __launch_bounds__(256) void prep_w(
    const float* __restrict__ Wq, const float* __restrict__ Wk,
    const float* __restrict__ Wv, const float* __restrict__ Wo,
    u16* __restrict__ WT, u16* __restrict__ WOT)
{
    int idx = blockIdx.x * 256 + threadIdx.x;  // 0..262143
    if (idx < 196608) {
        int j = idx >> 8, k = idx & 255;
        const float* W = (j < 256) ? Wq : (j < 512) ? Wk : Wv;
        WT[idx] = f2bf(W[k * 256 + (j & 255)]);
    } else {
        int t = idx - 196608;
        int j = t >> 8, k = t & 255;
        WOT[t] = f2bf(Wo[k * 256 + j]);
    }
}

// ---------------------------------------------------------------------------
// QKV projection: C[65536,768] = relu(X[65536,256] @ W + b), bf16 out.
// ---------------------------------------------------------------------------
__global__ __launch_bounds__(256, 2) void qkv_gemm(
    const float* __restrict__ X, const u16* __restrict__ WT,
    const float* __restrict__ bQ, const float* __restrict__ bK,
    const float* __restrict__ bV,
    u16* __restrict__ outQ, u16* __restrict__ outK, u16* __restrict__ outVT)
{
    __shared__ __align__(16) u16 As[128 * 256];  // 64KB, XOR-swizzled rows
    __shared__ __align__(16) u16 Bs[128 * 64];   // 16KB, XOR-swizzled rows
    const int tid = threadIdx.x;
    const int m0 = blockIdx.x * 128;

    #pragma unroll
    for (int i = 0; i < 32; ++i) {
        int flat = (i * 256 + tid) * 4;
        int r = flat >> 8, c = flat & 255;
        const f32x4 f = *reinterpret_cast<const f32x4*>(X + (size_t)(m0 + r) * 256 + c);
        ushort4v h;
        h.x = f2bf(f.x); h.y = f2bf(f.y); h.z = f2bf(f.z); h.w = f2bf(f.w);
        int byte = (r * 512 + c * 2) ^ ((r & 7) << 4);
        *reinterpret_cast<ushort4v*>(reinterpret_cast<char*>(As) + byte) = h;
    }

    const int lane = tid & 63, wid = tid >> 6;
    const int wr = wid >> 1, wc = wid & 1;
    const int lr = lane & 15, lg = lane >> 4;

    for (int cb = 0; cb < 6; ++cb) {
        const int jbase = cb * 128;
        f32x4 acc[4][4];
        #pragma unroll
        for (int a = 0; a < 4; ++a)
            #pragma unroll
            for (int b = 0; b < 4; ++b) acc[a][b] = (f32x4){0.f, 0.f, 0.f, 0.f};

        for (int kk = 0; kk < 256; kk += 64) {
            __syncthreads();
            #pragma unroll
            for (int i = 0; i < 4; ++i) {
                int e = (i * 256 + tid) * 8;
                int r = e >> 6, c = e & 63;
                ushort8 d = *reinterpret_cast<const ushort8*>(WT + (size_t)(jbase + r) * 256 + kk + c);
                int byte = (r * 128 + c * 2) ^ ((r & 7) << 4);
                *reinterpret_cast<ushort8*>(reinterpret_cast<char*>(Bs) + byte) = d;
            }
            __syncthreads();
            #pragma unroll
            for (int ks = 0; ks < 2; ++ks) {
                bf16x8 af[4], bfr[4];
                #pragma unroll
                for (int mt = 0; mt < 4; ++mt) {
                    int r = wr * 64 + mt * 16 + lr;
                    int byte = (r * 512 + (kk + ks * 32 + lg * 8) * 2) ^ ((r & 7) << 4);
                    af[mt] = *reinterpret_cast<const bf16x8*>(reinterpret_cast<const char*>(As) + byte);
                }
                #pragma unroll
                for (int nt = 0; nt < 4; ++nt) {
                    int r = wc * 64 + nt * 16 + lr;
                    int byte = (r * 128 + (ks * 32 + lg * 8) * 2) ^ ((r & 7) << 4);
                    bfr[nt] = *reinterpret_cast<const bf16x8*>(reinterpret_cast<const char*>(Bs) + byte);
                }
                #pragma unroll
                for (int mt = 0; mt < 4; ++mt)
                    #pragma unroll
                    for (int nt = 0; nt < 4; ++nt)
                        acc[mt][nt] = mfma16(af[mt], bfr[nt], acc[mt][nt]);
            }
        }
        const float* bias = (cb < 2) ? bQ : (cb < 4) ? bK : bV;
        float bcol[4];
        #pragma unroll
        for (int nt = 0; nt < 4; ++nt)
            bcol[nt] = bias[(jbase + wc * 64 + nt * 16 + lr) & 255];
        #pragma unroll
        for (int mt = 0; mt < 4; ++mt) {
            #pragma unroll
            for (int nt = 0; nt < 4; ++nt) {
                #pragma unroll
                for (int j = 0; j < 4; ++j) {
                    float v = fmaxf(acc[mt][nt][j] + bcol[nt], 0.f);
                    u16 h = f2bf(v);
                    int row = m0 + wr * 64 + mt * 16 + lg * 4 + j;
                    int col = jbase + wc * 64 + nt * 16 + lr;
                    if (cb < 2) {
                        outQ[(size_t)row * 256 + col] = h;
                    } else if (cb < 4) {
                        outK[(size_t)row * 256 + (col - 256)] = h;
                    } else {
                        int bb = row >> 9, n = row & 511;
                        outVT[(size_t)bb * 131072 + (size_t)(col - 512) * 512 + n] = h;
                    }
                }
            }
        }
    }
}

// ---------------------------------------------------------------------------
// Flash attention r8 = r4 structure + persistent Q in registers.
// 512 threads (8 waves x 16 q-rows), KVBLK=32, K/V double-buffered in LDS via
// global_load_lds (K source pre-swizzled), mask f32 prefetched 1 tile ahead
// and packed to bits (binary mask => p = bit ? s : -9e15), defer-rescale.
// Q fragments (qf[8], 32 VGPR) loaded ONCE — removes the per-kt Q re-read
// (512MB L2/HBM traffic + exposed latency at every QK^T head).
// ---------------------------------------------------------------------------
__global__ __launch_bounds__(512) void attn_kernel(
    const u16* __restrict__ Q, const u16* __restrict__ K,
    const u16* __restrict__ VT, const float* __restrict__ Mask,
    u16* __restrict__ Out)
{
    __shared__ __align__(16) u16 k_lds[2][32 * 256];  // 2 x 16KB, XOR-swizzled
    __shared__ __align__(16) u16 v_lds[2][256 * 32];  // 2 x 16KB, linear [h][key]
    __shared__ __align__(16) u16 p_lds[8][16 * 32];   // 8KB, per-wave P
    const int tid = threadIdx.x;          // 0..511
    const int b  = blockIdx.x & 127;      // batch; 4 blocks/batch on one XCD
    const int rb = blockIdx.x >> 7;       // 0..3
    const int lane = tid & 63, wid = tid >> 6;
    const int lr = lane & 15, lg = lane >> 4;
    const int n0 = rb * 128 + wid * 16;
    const u16* qbat = Q  + (size_t)b * 131072;
    const u16* kbat = K  + (size_t)b * 131072;
    const u16* vbat = VT + (size_t)b * 131072;
    const float* mrow = Mask + ((size_t)b * 512 + n0 + lg * 4) * 512;

    auto stage = [&](int buf, int kt) {
        #pragma unroll
        for (int i = 0; i < 2; ++i) {
            int p = (i * 512 + tid) * 16;
            // K: rows 512B; src col ^= (row&7)<<4
            int krow = p >> 9, kcol2 = p & 511;
            int scol2 = kcol2 ^ ((krow & 7) << 4);
            const char* gk = reinterpret_cast<const char*>(kbat + (size_t)(kt * 32 + krow) * 256) + scol2;
            char* lk = reinterpret_cast<char*>(k_lds[buf]) + i * 8192 + wid * 1024;
            gload_lds16(gk, lk);
            // V: rows 64B, linear
            int vrow = p >> 6, vcol2 = p & 63;
            const char* gv = reinterpret_cast<const char*>(vbat + (size_t)vrow * 512 + kt * 32) + vcol2;
            char* lv = reinterpret_cast<char*>(v_lds[buf]) + i * 8192 + wid * 1024;
            gload_lds16(gv, lv);
        }
    };

    // persistent Q fragments: rows n0+lr, all 256 K-dim (8 chunks of 32)
    bf16x8 qf[8];
    #pragma unroll
    for (int ks = 0; ks < 8; ++ks)
        qf[ks] = *reinterpret_cast<const bf16x8*>(
            qbat + (size_t)(n0 + lr) * 256 + ks * 32 + lg * 8);

    stage(0, 0);
    // prefetch mask tile kt=0
    float mf[2][4];
    #pragma unroll
    for (int ct = 0; ct < 2; ++ct)
        #pragma unroll
        for (int j = 0; j < 4; ++j)
            mf[ct][j] = __builtin_nontemporal_load(mrow + (size_t)j * 512 + ct * 16 + lr);

    f32x4 acc[16];
    #pragma unroll
    for (int i = 0; i < 16; ++i) acc[i] = (f32x4){0.f, 0.f, 0.f, 0.f};
    float mreg[4], lreg[4];
    #pragma unroll
    for (int j = 0; j < 4; ++j) { mreg[j] = -__builtin_inff(); lreg[j] = 0.f; }

    __syncthreads();

    for (int kt = 0; kt < 16; ++kt) {
        const int cur = kt & 1;
        if (kt < 15) stage(cur ^ 1, kt + 1);

        // pack current mask bits, then reuse regs to prefetch next tile
        u32 mb = 0;
        #pragma unroll
        for (int ct = 0; ct < 2; ++ct)
            #pragma unroll
            for (int j = 0; j < 4; ++j)
                mb |= (mf[ct][j] > 0.5f ? 1u : 0u) << (ct * 4 + j);
        if (kt < 15) {
            #pragma unroll
            for (int ct = 0; ct < 2; ++ct)
                #pragma unroll
                for (int j = 0; j < 4; ++j)
                    mf[ct][j] = __builtin_nontemporal_load(
                        mrow + (size_t)j * 512 + (kt + 1) * 32 + ct * 16 + lr);
        }

        // ---- QK^T: 16 rows x 32 keys per wave, Q from registers ----
        f32x4 s[2];
        s[0] = (f32x4){0.f, 0.f, 0.f, 0.f};
        s[1] = (f32x4){0.f, 0.f, 0.f, 0.f};
        const char* kbase = reinterpret_cast<const char*>(k_lds[cur]);
        __builtin_amdgcn_s_setprio(1);
        #pragma unroll
        for (int ks = 0; ks < 8; ++ks) {
            #pragma unroll
            for (int ct = 0; ct < 2; ++ct) {
                int krow = ct * 16 + lr;
                int byte = (krow * 512 + (ks * 32 + lg * 8) * 2) ^ ((krow & 7) << 4);
                bf16x8 kf = *reinterpret_cast<const bf16x8*>(kbase + byte);
                s[ct] = mfma16(qf[ks], kf, s[ct]);
            }
        }
        __builtin_amdgcn_s_setprio(0);

        // ---- mask select + online softmax (defer-rescale) ----
        float p[2][4];
        #pragma unroll
        for (int ct = 0; ct < 2; ++ct)
            #pragma unroll
            for (int j = 0; j < 4; ++j)
                p[ct][j] = ((mb >> (ct * 4 + j)) & 1u) ? s[ct][j] : -9.0e15f;

        float r0j[4];
        bool need = false;
        #pragma unroll
        for (int j = 0; j < 4; ++j) {
            float r0 = fmaxf(p[0][j], p[1][j]);
            r0 = fmaxf(r0, __shfl_xor(r0, 1));
            r0 = fmaxf(r0, __shfl_xor(r0, 2));
            r0 = fmaxf(r0, __shfl_xor(r0, 4));
            r0 = fmaxf(r0, __shfl_xor(r0, 8));
            r0j[j] = r0;
            need = need || (r0 > mreg[j]);
        }
        if (__any(need)) {
            #pragma unroll
            for (int j = 0; j < 4; ++j) {
                float mnew = fmaxf(mreg[j], r0j[j]);
                float sc = __expf(mreg[j] - mnew);
                mreg[j] = mnew;
                lreg[j] *= sc;
                #pragma unroll
                for (int ht = 0; ht < 16; ++ht) acc[ht][j] *= sc;
            }
        }
        #pragma unroll
        for (int j = 0; j < 4; ++j) {
            float ps = 0.f;
            #pragma unroll
            for (int ct = 0; ct < 2; ++ct) {
                float e = __expf(p[ct][j] - mreg[j]);
                p[ct][j] = e;
                ps += e;
            }
            lreg[j] += ps;
        }

        // ---- P (D-layout) -> per-wave LDS [16 rows][32 keys], 64B rows ----
        #pragma unroll
        for (int ct = 0; ct < 2; ++ct)
            #pragma unroll
            for (int j = 0; j < 4; ++j) {
                int byte = (lg * 4 + j) * 64 + (ct * 16 + lr) * 2;
                *reinterpret_cast<u16*>(reinterpret_cast<char*>(p_lds[wid]) + byte) = f2bf(p[ct][j]);
            }

        // ---- PV: acc[16 rows][256 h] += P[16][32] @ V[32][256] ----
        bf16x8 pf = *reinterpret_cast<const bf16x8*>(
            reinterpret_cast<const char*>(p_lds[wid]) + lr * 64 + lg * 16);
        const char* vbase = reinterpret_cast<const char*>(v_lds[cur]);
        __builtin_amdgcn_s_setprio(1);
        #pragma unroll
        for (int ht = 0; ht < 16; ++ht) {
            bf16x8 vf = *reinterpret_cast<const bf16x8*>(vbase + (ht * 16 + lr) * 64 + lg * 16);
            acc[ht] = mfma16(pf, vf, acc[ht]);
        }
        __builtin_amdgcn_s_setprio(0);

        __syncthreads();  // next tile staged (vmcnt drained); LDS reads done
    }

    // finalize: normalize and store bf16
    #pragma unroll
    for (int j = 0; j < 4; ++j) {
        float lt = lreg[j];
        lt += __shfl_xor(lt, 1);
        lt += __shfl_xor(lt, 2);
        lt += __shfl_xor(lt, 4);
        lt += __shfl_xor(lt, 8);
        float inv = 1.0f / lt;
        int qn = n0 + lg * 4 + j;
        u16* orow = Out + ((size_t)b * 512 + qn) * 256;
        #pragma unroll
        for (int ht = 0; ht < 16; ++ht)
            orow[ht * 16 + lr] = f2bf(acc[ht][j] * inv);
    }
}

// ---------------------------------------------------------------------------
// Output projection: Out[65536,256] = relu(A[65536,256](bf16) @ Wo + bo), f32.
// ---------------------------------------------------------------------------
__global__ __launch_bounds__(256, 2) void out_gemm(
    const u16* __restrict__ A, const u16* __restrict__ WOT,
    const float* __restrict__ bO, float* __restrict__ Out)
{
    __shared__ __align__(16) u16 As[128 * 256];
    __shared__ __align__(16) u16 Bs[128 * 64];
    const int tid = threadIdx.x;
    const int m0 = blockIdx.x * 128;

    #pragma unroll
    for (int i = 0; i < 16; ++i) {
        int e = (i * 256 + tid) * 8;
        int r = e >> 8, c = e & 255;
        ushort8 d = *reinterpret_cast<const ushort8*>(A + (size_t)(m0 + r) * 256 + c);
        int byte = (r * 512 + c * 2) ^ ((r & 7) << 4);
        *reinterpret_cast<ushort8*>(reinterpret_cast<char*>(As) + byte) = d;
    }

    const int lane = tid & 63, wid = tid >> 6;
    const int wr = wid >> 1, wc = wid & 1;
    const int lr = lane & 15, lg = lane >> 4;

    for (int cb = 0; cb < 2; ++cb) {
        const int jbase = cb * 128;
        f32x4 acc[4][4];
        #pragma unroll
        for (int a = 0; a < 4; ++a)
            #pragma unroll
            for (int b = 0; b < 4; ++b) acc[a][b] = (f32x4){0.f, 0.f, 0.f, 0.f};

        for (int kk = 0; kk < 256; kk += 64) {
            __syncthreads();
            #pragma unroll
            for (int i = 0; i < 4; ++i) {
                int e = (i * 256 + tid) * 8;
                int r = e >> 6, c = e & 63;
                ushort8 d = *reinterpret_cast<const ushort8*>(WOT + (size_t)(jbase + r) * 256 + kk + c);
                int byte = (r * 128 + c * 2) ^ ((r & 7) << 4);
                *reinterpret_cast<ushort8*>(reinterpret_cast<char*>(Bs) + byte) = d;
            }
            __syncthreads();
            #pragma unroll
            for (int ks = 0; ks < 2; ++ks) {
                bf16x8 af[4], bfr[4];
                #pragma unroll
                for (int mt = 0; mt < 4; ++mt) {
                    int r = wr * 64 + mt * 16 + lr;
                    int byte = (r * 512 + (kk + ks * 32 + lg * 8) * 2) ^ ((r & 7) << 4);
                    af[mt] = *reinterpret_cast<const bf16x8*>(reinterpret_cast<const char*>(As) + byte);
                }
                #pragma unroll
                for (int nt = 0; nt < 4; ++nt) {
                    int r = wc * 64 + nt * 16 + lr;
                    int byte = (r * 128 + (ks * 32 + lg * 8) * 2) ^ ((r & 7) << 4);
                    bfr[nt] = *reinterpret_cast<const bf16x8*>(reinterpret_cast<const char*>(Bs) + byte);
                }
                #pragma unroll
                for (int mt = 0; mt < 4; ++mt)
                    #pragma unroll
                    for (int nt = 0; nt < 4; ++nt)
                        acc[mt][nt] = mfma16(af[mt], bfr[nt], acc[mt][nt]);
            }
        }
        float bcol[4];
        #pragma unroll
        for (int nt = 0; nt < 4; ++nt)
            bcol[nt] = bO[jbase + wc * 64 + nt * 16 + lr];
        #pragma unroll
        for (int mt = 0; mt < 4; ++mt) {
            #pragma unroll
            for (int nt = 0; nt < 4; ++nt) {
                #pragma unroll
                for (int j = 0; j < 4; ++j) {
                    float v = fmaxf(acc[mt][nt][j] + bcol[nt], 0.f);
                    int row = m0 + wr * 64 + mt * 16 + lg * 4 + j;
                    int col = jbase + wc * 64 + nt * 16 + lr;
                    Out[(size_t)row * 256 + col] = v;
                }
            }
        }
    }
}

// ---------------------------------------------------------------------------
extern "C" void kernel_launch(void* const* d_in, const int* in_sizes, int n_in,
                              void* d_out, int out_size, void* d_ws, size_t ws_size,
                              hipStream_t stream) {
    const float* x    = (const float*)d_in[0];
    const float* mask = (const float*)d_in[1];
    const float* Wv   = (const float*)d_in[2];
    const float* bv   = (const float*)d_in[3];
    const float* Wk   = (const float*)d_in[4];
    const float* bk   = (const float*)d_in[5];
    const float* Wq   = (const float*)d_in[6];
    const float* bq   = (const float*)d_in[7];
    const float* Wo   = (const float*)d_in[8];
    const float* bo   = (const float*)d_in[9];
    float* out = (float*)d_out;

    char* ws = (char*)d_ws;
    u16* WT  = (u16*)(ws);                          // 768*256 bf16 = 384KB
    u16* WOT = (u16*)(ws + 393216);                 // 256*256 bf16 = 128KB
    u16* Qb  = (u16*)(ws + 524288);                 // 33.55MB (also attn out)
    u16* Kb  = (u16*)(ws + 524288 + 33554432);      // 33.55MB
    u16* VTb = (u16*)(ws + 524288 + 2 * 33554432);  // 33.55MB, [b][h][n]

    prep_w<<<1024, 256, 0, stream>>>(Wq, Wk, Wv, Wo, WT, WOT);
    qkv_gemm<<<512, 256, 0, stream>>>(x, WT, bq, bk, bv, Qb, Kb, VTb);
    attn_kernel<<<512, 512, 0, stream>>>(Qb, Kb, VTb, mask, Qb);
    out_gemm<<<512, 256, 0, stream>>>(Qb, WOT, bo, out);
}